// Round 3
// baseline (136.897 us; speedup 1.0000x reference)
//
#include <hip/hip_runtime.h>
#include <math.h>

#define NUM_EMB 512
#define DIMV 65          // 65
#define DD   64          // DIM-1
#define BB   2048
#define NN   256

__device__ __forceinline__ float gelu_exact(float x) {
    return 0.5f * x * (1.0f + erff(x * 0.7071067811865475f));
}

// ---------------------------------------------------------------------------
// Kernel 1: build W = H0 @ H1 @ ... @ H63 per embedding, scale last column,
// store TRANSPOSED:  WgT[e][c][d] = W[e][d][c]  (so apply_W's per-lane column
// load is 16 contiguous float4s). Householder right-multiply as matvec +
// rank-1 update: W <- W - (2/||v||^2) (W v) v^T. Dot uses 4 partial chains
// to cut the serial-FMA critical path. Also echoes r_idx into out tail.
// ---------------------------------------------------------------------------
__global__ __launch_bounds__(256) void build_W(const float* __restrict__ emb,
                                               const float* __restrict__ flip_sign,
                                               const int*   __restrict__ r_idx,
                                               float* __restrict__ WgT,
                                               float* __restrict__ out) {
    __shared__ float v_lds[DD * DD];
    __shared__ float s_lds[DD];
    const int e = blockIdx.x;
    const int t = threadIdx.x;
    const int r = t >> 2;
    const int q = t & 3;

    const float* erow = emb + (size_t)e * (DD * DD);
    #pragma unroll
    for (int p = 0; p < 16; ++p) {
        int idx = p * 256 + t;
        v_lds[idx] = gelu_exact(erow[idx]);
    }

    // r_idx passthrough: output 1 lives at out[BB*NN*DIMV + b]
    if (t < 4) {
        int bi = e * 4 + t;
        out[(size_t)BB * NN * DIMV + bi] = (float)r_idx[bi];
    }
    __syncthreads();

    {
        const float* vr = &v_lds[r * DD + q * 16];
        float ss = 0.f;
        #pragma unroll
        for (int k = 0; k < 16; ++k) ss += vr[k] * vr[k];
        ss += __shfl_xor(ss, 1);
        ss += __shfl_xor(ss, 2);
        if (q == 0) s_lds[r] = 2.0f / ss;
    }
    __syncthreads();

    float Wq[16];
    #pragma unroll
    for (int k = 0; k < 16; ++k) Wq[k] = ((q * 16 + k) == r) ? 1.0f : 0.0f;

    for (int w = 0; w < DD; ++w) {
        const float* vr = &v_lds[w * DD + q * 16];
        float vv[16];
        *(float4*)&vv[0]  = *(const float4*)&vr[0];
        *(float4*)&vv[4]  = *(const float4*)&vr[4];
        *(float4*)&vv[8]  = *(const float4*)&vr[8];
        *(float4*)&vv[12] = *(const float4*)&vr[12];
        // 4 partial chains -> shorter critical path than one 16-FMA chain
        float p0 = Wq[0] * vv[0],  p1 = Wq[1] * vv[1];
        float p2 = Wq[2] * vv[2],  p3 = Wq[3] * vv[3];
        #pragma unroll
        for (int k = 4; k < 16; k += 4) {
            p0 += Wq[k]     * vv[k];
            p1 += Wq[k + 1] * vv[k + 1];
            p2 += Wq[k + 2] * vv[k + 2];
            p3 += Wq[k + 3] * vv[k + 3];
        }
        float p = (p0 + p1) + (p2 + p3);
        p += __shfl_xor(p, 1);
        p += __shfl_xor(p, 2);
        const float sc = s_lds[w] * p;
        #pragma unroll
        for (int k = 0; k < 16; ++k) Wq[k] -= sc * vv[k];
    }

    // W[:, :, -1] *= flip_sign  (column 63 = q==3, k==15)
    if (q == 3) Wq[15] *= flip_sign[0];

    // store transposed: WgT[e][16q+k][r] = Wq[k]
    float* wd = WgT + (size_t)e * (DD * DD) + r;
    #pragma unroll
    for (int k = 0; k < 16; ++k)
        wd[(16 * q + k) * DD] = Wq[k];
}

// ---------------------------------------------------------------------------
// Kernel 2: out[b,n,0] = x[b,n,0];  out[b,n,1+c] = sum_d x[b,n,1+d] * W[d][c]
// 256-thread block = 4 waves, one b and a 64-row n-tile; wave w owns rows
// 16w..16w+15, lane = output column c.
//  - W column c held in REGISTERS: wcv[16] (float4) loaded once from WgT
//    (contiguous per lane, L2-resident).
//  - x staged per-wave into LDS stripped of col0 (x_lds[row*64+d], rows 16B
//    aligned); each wave writes only rows it reads -> NO __syncthreads.
//  - Inner loop: uniform-address ds_read_b128 broadcasts of x (conflict-free)
//    + FMAs against register-resident W. 4 rows in flight -> 4 indep chains.
//  - Stores: one coalesced dword per row (lane c -> out[...+1+c]).
// ---------------------------------------------------------------------------
__global__ __launch_bounds__(256, 4) void apply_W(const float* __restrict__ x,
                                                  const int*   __restrict__ r_idx,
                                                  const float* __restrict__ WgT,
                                                  float* __restrict__ out) {
    __shared__ float x_lds[64 * DD];      // 16384 B, stripped layout
    const int blk  = blockIdx.x;
    const int b    = blk >> 2;
    const int tile = blk & 3;
    const size_t rowbase = (size_t)b * NN + tile * 64;
    const int t    = threadIdx.x;
    const int lane = t & 63;
    const int w    = t >> 6;
    const int r0   = w * 16;

    const int e = r_idx[b];   // uniform -> scalar load

    // W column 'lane' -> registers (16 x float4, contiguous 256B per lane)
    float4 wcv[16];
    {
        const float4* wsrc = (const float4*)(WgT + (size_t)e * (DD * DD) + lane * DD);
        #pragma unroll
        for (int k = 0; k < 16; ++k) wcv[k] = wsrc[k];
    }

    // stage this wave's 16 rows, stripping col 0: x_lds[row*64+d] = x[row][1+d]
    // global: 64 consecutive dwords per instr (coalesced); LDS: linear dwords.
    {
        const float* xb = x + rowbase * DIMV;
        #pragma unroll
        for (int k = 0; k < 16; ++k) {
            int idx = w * 1024 + k * 64 + lane;   // this wave's slice
            int row = idx >> 6, d = idx & 63;     // row = r0 + k
            x_lds[idx] = xb[row * DIMV + 1 + d];
        }
    }
    // col-0 passthrough for this wave's rows (lines are L1-hot from stage)
    if (lane < 16) {
        size_t gr = rowbase + r0 + lane;
        out[gr * DIMV] = x[gr * DIMV];
    }

    // compute: 4 groups of 4 rows, acc chains independent
    #pragma unroll
    for (int g = 0; g < 4; ++g) {
        const float* xr = &x_lds[(r0 + 4 * g) * DD];
        float acc0 = 0.f, acc1 = 0.f, acc2 = 0.f, acc3 = 0.f;
        #pragma unroll
        for (int kb = 0; kb < 16; ++kb) {
            float4 a0 = *(const float4*)&xr[0 * DD + 4 * kb];   // uniform bcast
            float4 a1 = *(const float4*)&xr[1 * DD + 4 * kb];
            float4 a2 = *(const float4*)&xr[2 * DD + 4 * kb];
            float4 a3 = *(const float4*)&xr[3 * DD + 4 * kb];
            const float4 wk = wcv[kb];
            acc0 += a0.x * wk.x + a0.y * wk.y + a0.z * wk.z + a0.w * wk.w;
            acc1 += a1.x * wk.x + a1.y * wk.y + a1.z * wk.z + a1.w * wk.w;
            acc2 += a2.x * wk.x + a2.y * wk.y + a2.z * wk.z + a2.w * wk.w;
            acc3 += a3.x * wk.x + a3.y * wk.y + a3.z * wk.z + a3.w * wk.w;
        }
        size_t gr = rowbase + r0 + 4 * g;
        out[(gr + 0) * DIMV + 1 + lane] = acc0;   // coalesced across lanes
        out[(gr + 1) * DIMV + 1 + lane] = acc1;
        out[(gr + 2) * DIMV + 1 + lane] = acc2;
        out[(gr + 3) * DIMV + 1 + lane] = acc3;
    }
}

extern "C" void kernel_launch(void* const* d_in, const int* in_sizes, int n_in,
                              void* d_out, int out_size, void* d_ws, size_t ws_size,
                              hipStream_t stream) {
    const float* x         = (const float*)d_in[0];
    const int*   r_idx     = (const int*)d_in[1];
    const float* emb       = (const float*)d_in[2];
    const float* flip_sign = (const float*)d_in[3];
    float* out = (float*)d_out;
    float* WgT = (float*)d_ws;   // 512 * 64 * 64 * 4 = 8 MB scratch (W^T)

    build_W<<<NUM_EMB, 256, 0, stream>>>(emb, flip_sign, r_idx, WgT, out);
    apply_W<<<BB * 4, 256, 0, stream>>>(x, r_idx, WgT, out);
}